// Round 1
// baseline (879.205 us; speedup 1.0000x reference)
//
#include <hip/hip_runtime.h>

// ---------------------------------------------------------------------------
// MXFP4 two-layer quant model: y = (x @ dq(W1)^T + b1) @ dq(W2)^T + b2
// T=8192, D=4096, GROUP=32.
// Strategy: dequant W -> bf16 (exact: fp4 * 2^k fits bf16), x/h -> bf16,
// two m97-style bf16 MFMA GEMMs (128x128 tile, BK=32, global_load_lds x16).
// Workspace: Xb(64MB) | Hb(64MB) | Wd(32MB) = 160MB.
// ---------------------------------------------------------------------------

typedef __bf16 bf16;
typedef bf16 bf16x8 __attribute__((ext_vector_type(8)));
typedef float f32x4 __attribute__((ext_vector_type(4)));
typedef int intx4 __attribute__((ext_vector_type(4)));

#define T_DIM 8192
#define D_DIM 4096

__device__ __forceinline__ void gld_lds16(const void* g, void* l) {
    __builtin_amdgcn_global_load_lds(
        (const __attribute__((address_space(1))) void*)g,
        (__attribute__((address_space(3))) void*)l,
        16, 0, 0);
}

// ---- dequant W: codes[D,D] int32 in [0,16), scales[D,D/32] -> bf16 [D,D] ----
__global__ __launch_bounds__(256) void dequant_kernel(
    const int* __restrict__ codes, const float* __restrict__ scales,
    bf16* __restrict__ out)
{
    const size_t tid = (size_t)blockIdx.x * 256 + threadIdx.x;
    const size_t e = tid * 8;                 // 8 elements per thread, same group
    const int row = (int)(e >> 12);           // / 4096
    const int col = (int)(e & 4095);
    const float s = scales[(size_t)row * (D_DIM / 32) + (col >> 5)];
    const intx4 c0 = *(const intx4*)(codes + e);
    const intx4 c1 = *(const intx4*)(codes + e + 4);
    bf16x8 o;
#pragma unroll
    for (int i = 0; i < 8; ++i) {
        const int c = (i < 4) ? c0[i] : c1[i - 4];
        // E2M1 magnitudes x2 packed in nibbles: {0,1,2,3,4,6,8,12}
        float v = (float)((0xC8643210u >> ((c & 7) * 4)) & 0xF) * 0.5f;
        v = (c & 8) ? -v : v;
        o[i] = (bf16)(v * s);
    }
    *(bf16x8*)(out + e) = o;
}

// ---- fp32 -> bf16 ----
__global__ __launch_bounds__(256) void f32_to_bf16_kernel(
    const float* __restrict__ in, bf16* __restrict__ out)
{
    const size_t tid = (size_t)blockIdx.x * 256 + threadIdx.x;
    const size_t e = tid * 8;
    const float4 a = *(const float4*)(in + e);
    const float4 b = *(const float4*)(in + e + 4);
    bf16x8 o;
    o[0] = (bf16)a.x; o[1] = (bf16)a.y; o[2] = (bf16)a.z; o[3] = (bf16)a.w;
    o[4] = (bf16)b.x; o[5] = (bf16)b.y; o[6] = (bf16)b.z; o[7] = (bf16)b.w;
    *(bf16x8*)(out + e) = o;
}

// ---- GEMM: C[M,N] = A[M,K] @ B[N,K]^T + bias, A/B bf16, acc fp32 ----
// 128x128 tile, BK=32, 256 threads (4 waves 2x2, each 64x64 via 4x4 MFMA tiles)
template <bool OUT_BF16>
__global__ __launch_bounds__(256, 2) void gemm_bt_kernel(
    const bf16* __restrict__ A, const bf16* __restrict__ B,
    const float* __restrict__ bias, void* __restrict__ Cout,
    int M, int N, int K)
{
    __shared__ bf16 As[128 * 32];   // 8KB, row-major, no padding (global_load_lds)
    __shared__ bf16 Bs[128 * 32];

    const int t = threadIdx.x;
    const int wave = t >> 6;
    const int lane = t & 63;
    const int m0 = blockIdx.y * 128;
    const int n0 = blockIdx.x * 128;
    const int wm = (wave & 1) * 64;
    const int wn = (wave >> 1) * 64;

    f32x4 acc[4][4] = {};

    // staging geometry: tile = 128 rows x 64 bytes; thread t covers bytes
    // q*4096 + t*16 for q in {0,1}
    const int off0 = t * 16;
    const int row0 = off0 >> 6, colb0 = off0 & 63;
    const int off1 = 4096 + t * 16;
    const int row1 = off1 >> 6, colb1 = off1 & 63;
    const int ldsbase = (t & 0xC0) * 16;      // wave-uniform: wave*1024 bytes

    const bf16* pa0 = A + (size_t)(m0 + row0) * K + (colb0 >> 1);
    const bf16* pa1 = A + (size_t)(m0 + row1) * K + (colb1 >> 1);
    const bf16* pb0 = B + (size_t)(n0 + row0) * K + (colb0 >> 1);
    const bf16* pb1 = B + (size_t)(n0 + row1) * K + (colb1 >> 1);

    const int fr = lane & 15;      // A/B operand: outer index = lane & 15
    const int quad = lane >> 4;    // k block: quad*8

    for (int k0 = 0; k0 < K; k0 += 32) {
        gld_lds16(pa0 + k0, (char*)As + ldsbase);
        gld_lds16(pa1 + k0, (char*)As + 4096 + ldsbase);
        gld_lds16(pb0 + k0, (char*)Bs + ldsbase);
        gld_lds16(pb1 + k0, (char*)Bs + 4096 + ldsbase);
        __syncthreads();

        bf16x8 af[4], bff[4];
#pragma unroll
        for (int i = 0; i < 4; ++i) {
            af[i]  = *(const bf16x8*)(As + (wm + i * 16 + fr) * 32 + quad * 8);
            bff[i] = *(const bf16x8*)(Bs + (wn + i * 16 + fr) * 32 + quad * 8);
        }
#pragma unroll
        for (int i = 0; i < 4; ++i)
#pragma unroll
            for (int j = 0; j < 4; ++j)
                acc[i][j] = __builtin_amdgcn_mfma_f32_16x16x32_bf16(
                    af[i], bff[j], acc[i][j], 0, 0, 0);
        __syncthreads();
    }

    // epilogue: D row = quad*4 + r (M), col = lane&15 (N)
    const int cn = lane & 15;
#pragma unroll
    for (int j = 0; j < 4; ++j) {
        const int gn = n0 + wn + j * 16 + cn;
        const float bv = bias[gn];
#pragma unroll
        for (int i = 0; i < 4; ++i) {
            const int gmBase = m0 + wm + i * 16 + quad * 4;
#pragma unroll
            for (int r = 0; r < 4; ++r) {
                const float v = acc[i][j][r] + bv;
                const size_t idx = (size_t)(gmBase + r) * N + gn;
                if (OUT_BF16) ((bf16*)Cout)[idx] = (bf16)v;
                else          ((float*)Cout)[idx] = v;
            }
        }
    }
}

extern "C" void kernel_launch(void* const* d_in, const int* in_sizes, int n_in,
                              void* d_out, int out_size, void* d_ws, size_t ws_size,
                              hipStream_t stream)
{
    const float* x         = (const float*)d_in[0];
    const int*   w1_codes  = (const int*)d_in[1];
    const float* w1_scales = (const float*)d_in[2];
    const float* b1        = (const float*)d_in[3];
    const int*   w2_codes  = (const int*)d_in[4];
    const float* w2_scales = (const float*)d_in[5];
    const float* b2        = (const float*)d_in[6];
    float* y = (float*)d_out;

    char* ws = (char*)d_ws;
    bf16* Xb = (bf16*)ws;                                      // 64 MB
    bf16* Hb = (bf16*)(ws + (size_t)T_DIM * D_DIM * 2);        // 64 MB
    bf16* Wd = (bf16*)(ws + (size_t)2 * T_DIM * D_DIM * 2);    // 32 MB (W1 then W2)

    // x -> bf16
    f32_to_bf16_kernel<<<(T_DIM * (size_t)D_DIM) / 8 / 256, 256, 0, stream>>>(x, Xb);
    // dequant W1
    dequant_kernel<<<(D_DIM * (size_t)D_DIM) / 8 / 256, 256, 0, stream>>>(w1_codes, w1_scales, Wd);
    // GEMM1: Hb = Xb @ Wd^T + b1 (bf16 out)
    dim3 grid(D_DIM / 128, T_DIM / 128);
    gemm_bt_kernel<true><<<grid, 256, 0, stream>>>(Xb, Wd, b1, (void*)Hb,
                                                   T_DIM, D_DIM, D_DIM);
    // dequant W2 (reuses Wd; stream order serializes vs GEMM1)
    dequant_kernel<<<(D_DIM * (size_t)D_DIM) / 8 / 256, 256, 0, stream>>>(w2_codes, w2_scales, Wd);
    // GEMM2: y = Hb @ Wd^T + b2 (fp32 out)
    gemm_bt_kernel<false><<<grid, 256, 0, stream>>>(Hb, Wd, b2, (void*)y,
                                                    T_DIM, D_DIM, D_DIM);
}